// Round 1
// baseline (124.906 us; speedup 1.0000x reference)
//
#include <hip/hip_runtime.h>

#define T_LEN 32768
#define DIM   300
#define NP    5      // PAT_LEN - 1 superdiagonal entries
#define TB    16     // window starts per block
#define HALO  4

__device__ __forceinline__ float fast_sigmoid(float z) {
    return 1.0f / (1.0f + __expf(-z));
}

__global__ __launch_bounds__(256) void softpat_kernel(
    const int*   __restrict__ doc,   // [T]
    const float* __restrict__ emb,   // [VOCAB, 300]
    const float* __restrict__ w,     // [6, 6, 300]
    const float* __restrict__ b,     // [6, 6]
    float*       __restrict__ out)   // [1]
{
    __shared__ float lds_w[NP][DIM];
    __shared__ float lds_b[NP];
    __shared__ float lds_v[TB + HALO][NP];

    const int tid  = threadIdx.x;
    const int lane = tid & 63;
    const int wave = tid >> 6;
    const int t0   = blockIdx.x * TB;

    // Stage superdiagonal weight rows: w[i][i+1] -> flat offset (7i+1)*300
    for (int idx = tid; idx < NP * DIM; idx += 256) {
        int i = idx / DIM;
        int d = idx - i * DIM;
        lds_w[i][d] = w[(7 * i + 1) * DIM + d];
    }
    if (tid < NP) lds_b[tid] = b[7 * tid + 1];
    __syncthreads();

    // Each wave computes vals[] for 4 main t's + 1 halo t (block covers 20 t's).
    for (int k = 0; k < 5; ++k) {
        const int tt = (k < 4) ? (wave * 4 + k) : (TB + wave);  // local t index [0,20)
        const int t  = t0 + tt;
        const bool valid = (t < T_LEN);

        float a0 = 0.f, a1 = 0.f, a2 = 0.f, a3 = 0.f, a4 = 0.f;
        if (valid) {
            const float* __restrict__ xrow = emb + (size_t)doc[t] * DIM;
            #pragma unroll
            for (int it = 0; it < 5; ++it) {
                const int d = it * 64 + lane;
                if (d < DIM) {
                    const float x = xrow[d];
                    a0 += x * lds_w[0][d];
                    a1 += x * lds_w[1][d];
                    a2 += x * lds_w[2][d];
                    a3 += x * lds_w[3][d];
                    a4 += x * lds_w[4][d];
                }
            }
        }
        // 64-lane butterfly reduction of the 5 partial dots
        #pragma unroll
        for (int off = 32; off > 0; off >>= 1) {
            a0 += __shfl_xor(a0, off);
            a1 += __shfl_xor(a1, off);
            a2 += __shfl_xor(a2, off);
            a3 += __shfl_xor(a3, off);
            a4 += __shfl_xor(a4, off);
        }
        if (lane == 0) {
            lds_v[tt][0] = valid ? fast_sigmoid(a0 + lds_b[0]) : 0.f;
            lds_v[tt][1] = valid ? fast_sigmoid(a1 + lds_b[1]) : 0.f;
            lds_v[tt][2] = valid ? fast_sigmoid(a2 + lds_b[2]) : 0.f;
            lds_v[tt][3] = valid ? fast_sigmoid(a3 + lds_b[3]) : 0.f;
            lds_v[tt][4] = valid ? fast_sigmoid(a4 + lds_b[4]) : 0.f;
        }
    }
    __syncthreads();

    // Wave 0: window products for the block's 16 starts, reduce, one atomic.
    if (wave == 0) {
        float p = 0.f;
        const int s = t0 + lane;
        if (lane < TB && s <= T_LEN - (NP)) {
            p = lds_v[lane + 0][0] * lds_v[lane + 1][1] * lds_v[lane + 2][2]
              * lds_v[lane + 3][3] * lds_v[lane + 4][4];
        }
        #pragma unroll
        for (int off = 32; off > 0; off >>= 1) p += __shfl_xor(p, off);
        if (lane == 0) atomicAdd(out, p);
    }
}

extern "C" void kernel_launch(void* const* d_in, const int* in_sizes, int n_in,
                              void* d_out, int out_size, void* d_ws, size_t ws_size,
                              hipStream_t stream) {
    const int*   doc = (const int*)  d_in[0];
    const float* emb = (const float*)d_in[1];
    const float* w   = (const float*)d_in[2];
    const float* b   = (const float*)d_in[3];
    float*       out = (float*)d_out;

    hipMemsetAsync(out, 0, sizeof(float), stream);

    const int blocks = T_LEN / TB;  // 2048
    softpat_kernel<<<blocks, 256, 0, stream>>>(doc, emb, w, b, out);
}

// Round 3
// 102.611 us; speedup vs baseline: 1.2173x; 1.2173x over previous
//
#include <hip/hip_runtime.h>

#define T_LEN 32768
#define DIM   300
#define NCH   75     // DIM/4 float4 chunks per row
#define NP    5      // superdiagonal entries

__device__ __forceinline__ float fast_sigmoid(float z) {
    return 1.0f / (1.0f + __expf(-z));
}

// Each 16-lane group computes the 5 superdiagonal dot products for one t.
// vals stored SoA: vals[i][t] = sigmoid(w[i,i+1].x_t + b[i,i+1])
__global__ __launch_bounds__(256) void vals_kernel(
    const int*   __restrict__ doc,   // [T]
    const float* __restrict__ emb,   // [VOCAB, 300]
    const float* __restrict__ w,     // [6, 6, 300]
    const float* __restrict__ b,     // [6, 6]
    float*       __restrict__ vals)  // ws: [5][T]
{
    __shared__ float lds_w[NP][DIM];
    __shared__ float lds_b[NP];

    const int tid = threadIdx.x;

    // Stage superdiagonal weight rows (w[i][i+1] at flat row 7i+1) via float4.
    // (7i+1)*300*4 B is 16B-aligned; lds_w row stride 1200 B also 16B-aligned.
    for (int c = tid; c < NP * NCH; c += 256) {
        const int i  = c / NCH;
        const int cc = c - i * NCH;
        const float4 v = *reinterpret_cast<const float4*>(w + (size_t)(7 * i + 1) * DIM + 4 * cc);
        *reinterpret_cast<float4*>(&lds_w[i][4 * cc]) = v;
    }
    if (tid < NP) lds_b[tid] = b[7 * tid + 1];
    __syncthreads();

    const int g   = tid >> 4;       // group 0..15 within block -> one t each
    const int sub = tid & 15;
    const int t   = blockIdx.x * 16 + g;

    const float* __restrict__ xrow = emb + (size_t)doc[t] * DIM;

    float a0 = 0.f, a1 = 0.f, a2 = 0.f, a3 = 0.f, a4 = 0.f;
    #pragma unroll
    for (int r = 0; r < 5; ++r) {
        const int c = sub + 16 * r;
        if (c < NCH) {
            const float4 xv = *reinterpret_cast<const float4*>(xrow + 4 * c);
            const float4 w0 = *reinterpret_cast<const float4*>(&lds_w[0][4 * c]);
            const float4 w1 = *reinterpret_cast<const float4*>(&lds_w[1][4 * c]);
            const float4 w2 = *reinterpret_cast<const float4*>(&lds_w[2][4 * c]);
            const float4 w3 = *reinterpret_cast<const float4*>(&lds_w[3][4 * c]);
            const float4 w4 = *reinterpret_cast<const float4*>(&lds_w[4][4 * c]);
            a0 += xv.x * w0.x + xv.y * w0.y + xv.z * w0.z + xv.w * w0.w;
            a1 += xv.x * w1.x + xv.y * w1.y + xv.z * w1.z + xv.w * w1.w;
            a2 += xv.x * w2.x + xv.y * w2.y + xv.z * w2.z + xv.w * w2.w;
            a3 += xv.x * w3.x + xv.y * w3.y + xv.z * w3.z + xv.w * w3.w;
            a4 += xv.x * w4.x + xv.y * w4.y + xv.z * w4.z + xv.w * w4.w;
        }
    }

    // 16-lane butterfly (xor offsets < 16 stay inside the group)
    #pragma unroll
    for (int off = 8; off >= 1; off >>= 1) {
        a0 += __shfl_xor(a0, off);
        a1 += __shfl_xor(a1, off);
        a2 += __shfl_xor(a2, off);
        a3 += __shfl_xor(a3, off);
        a4 += __shfl_xor(a4, off);
    }

    if (sub < NP) {
        const float a = (sub == 0) ? a0 : (sub == 1) ? a1 : (sub == 2) ? a2
                       : (sub == 3) ? a3 : a4;
        vals[sub * T_LEN + t] = fast_sigmoid(a + lds_b[sub]);
    }
}

__global__ __launch_bounds__(256) void reduce_kernel(
    const float* __restrict__ vals,  // [5][T]
    float*       __restrict__ out)
{
    const int s = blockIdx.x * 256 + threadIdx.x;
    float p = 0.f;
    if (s <= T_LEN - NP) {
        p = vals[s]
          * vals[1 * T_LEN + s + 1]
          * vals[2 * T_LEN + s + 2]
          * vals[3 * T_LEN + s + 3]
          * vals[4 * T_LEN + s + 4];
    }
    #pragma unroll
    for (int off = 32; off >= 1; off >>= 1) p += __shfl_xor(p, off);

    __shared__ float partial[4];
    if ((threadIdx.x & 63) == 0) partial[threadIdx.x >> 6] = p;
    __syncthreads();
    if (threadIdx.x == 0)
        atomicAdd(out, partial[0] + partial[1] + partial[2] + partial[3]);
}

extern "C" void kernel_launch(void* const* d_in, const int* in_sizes, int n_in,
                              void* d_out, int out_size, void* d_ws, size_t ws_size,
                              hipStream_t stream) {
    const int*   doc = (const int*)  d_in[0];
    const float* emb = (const float*)d_in[1];
    const float* w   = (const float*)d_in[2];
    const float* b   = (const float*)d_in[3];
    float*       out = (float*)d_out;
    float*       vals = (float*)d_ws;   // 5*T*4 = 640 KB

    hipMemsetAsync(out, 0, sizeof(float), stream);

    vals_kernel<<<T_LEN / 16, 256, 0, stream>>>(doc, emb, w, b, vals);
    reduce_kernel<<<(T_LEN + 255) / 256, 256, 0, stream>>>(vals, out);
}